// Round 1
// baseline (202.493 us; speedup 1.0000x reference)
//
#include <hip/hip_runtime.h>

typedef unsigned short u16;
typedef unsigned int u32;
typedef __attribute__((ext_vector_type(8))) __bf16 bf16x8;
typedef __attribute__((ext_vector_type(4))) float f32x4;
typedef __attribute__((ext_vector_type(4))) u16 u16x4;

#define DEVFN static __device__ __forceinline__

constexpr int S_ = 2048;
constexpr int D_ = 1024;
constexpr float SCALE_ = 0.03125f; // 1/sqrt(1024)

DEVFN u16 f2bf(float f) {
  u32 u = __builtin_bit_cast(u32, f);
  u32 r = (u + 0x7fffu + ((u >> 16) & 1u)) >> 16;
  return (u16)r;
}
DEVFN float bf2f(u16 h) {
  u32 u = ((u32)h) << 16;
  return __builtin_bit_cast(float, u);
}
DEVFN void gld16(const u16* g, u16* l) {
  __builtin_amdgcn_global_load_lds(
      (const __attribute__((address_space(1))) u32*)g,
      (__attribute__((address_space(3))) u32*)l, 16, 0, 0);
}

// ---------------- x fp32 -> bf16 ----------------
__global__ __launch_bounds__(256) void cvt_x_kernel(const float* __restrict__ x,
                                                    u16* __restrict__ xb) {
  int i = blockIdx.x * 256 + threadIdx.x; // 2,097,152 threads, 4 elems each
  float4 v = ((const float4*)x)[i];
  u16x4 o = {f2bf(v.x), f2bf(v.y), f2bf(v.z), f2bf(v.w)};
  ((u16x4*)xb)[i] = o;
}

// ---------------- W [K][N] fp32 -> Wt [N][K] bf16 ----------------
__global__ __launch_bounds__(256) void transpose_w_kernel(const float* __restrict__ W,
                                                          u16* __restrict__ Wt) {
  __shared__ float t[32][33];
  int tx = threadIdx.x, ty = threadIdx.y; // block (32,8)
  int n0 = blockIdx.x * 32, k0 = blockIdx.y * 32;
#pragma unroll
  for (int i = 0; i < 4; ++i)
    t[ty + i * 8][tx] = W[(size_t)(k0 + ty + i * 8) * D_ + n0 + tx];
  __syncthreads();
#pragma unroll
  for (int i = 0; i < 4; ++i)
    Wt[(size_t)(n0 + ty + i * 8) * D_ + k0 + tx] = f2bf(t[tx][ty + i * 8]);
}

// ---------------- generic NT GEMM: C = A[M][K] * Bt[N][K]^T ----------------
// MODE 0: bf16 out row-major [M][N]
// MODE 1: bf16 out transposed per batch: Vt[b][n][s], m = b*2048+s
// MODE 2: bf16 out row-major per batch (scores), causal tile skip
// MODE 3: fp32 out row-major per batch (PV), causal K truncation
template <int MODE>
__global__ __launch_bounds__(256) void gemm_nt(const u16* __restrict__ A,
                                               const u16* __restrict__ Bt,
                                               void* __restrict__ C, int K, int N,
                                               long sA, long sB, long sC) {
  int tm = blockIdx.x, tn = blockIdx.y, z = blockIdx.z;
  if (MODE == 2 && tn > tm) return;
  int tid = threadIdx.x;
  int lane = tid & 63;
  int w = tid >> 6;
  int wm = w >> 1, wn = w & 1;

  __shared__ u16 lsA[2][128 * 32];
  __shared__ u16 lsB[2][128 * 32];

  const u16* Ab = A + (size_t)z * sA + (size_t)tm * 128 * K;
  const u16* Bb = Bt + (size_t)z * sB + (size_t)tn * 128 * K;

  int nk = (MODE == 3) ? (tm + 1) * 4 : (K >> 5);

  int srow = tid >> 2;      // 0..63
  int scol = (tid & 3) * 8; // elem offset in k

  f32x4 acc[4][4] = {};

  // prologue: stage k-tile 0 into buffer 0
#pragma unroll
  for (int i = 0; i < 2; ++i) {
    gld16(Ab + (size_t)(i * 64 + srow) * K + scol, &lsA[0][(i * 64 + srow) * 32 + scol]);
    gld16(Bb + (size_t)(i * 64 + srow) * K + scol, &lsB[0][(i * 64 + srow) * 32 + scol]);
  }
  __syncthreads();

  int arow = wm * 64 + (lane & 15);
  int brow = wn * 64 + (lane & 15);
  int kg = (lane >> 4) * 8;

  for (int kt = 0; kt < nk; ++kt) {
    int cur = kt & 1;
    if (kt + 1 < nk) {
      int k0 = (kt + 1) << 5;
#pragma unroll
      for (int i = 0; i < 2; ++i) {
        gld16(Ab + (size_t)(i * 64 + srow) * K + k0 + scol,
              &lsA[cur ^ 1][(i * 64 + srow) * 32 + scol]);
        gld16(Bb + (size_t)(i * 64 + srow) * K + k0 + scol,
              &lsB[cur ^ 1][(i * 64 + srow) * 32 + scol]);
      }
    }
    bf16x8 aF[4], bF[4];
#pragma unroll
    for (int f = 0; f < 4; ++f) {
      aF[f] = *(const bf16x8*)&lsA[cur][(arow + f * 16) * 32 + kg];
      bF[f] = *(const bf16x8*)&lsB[cur][(brow + f * 16) * 32 + kg];
    }
#pragma unroll
    for (int fm = 0; fm < 4; ++fm)
#pragma unroll
      for (int fn = 0; fn < 4; ++fn)
        acc[fm][fn] = __builtin_amdgcn_mfma_f32_16x16x32_bf16(aF[fm], bF[fn],
                                                              acc[fm][fn], 0, 0, 0);
    __syncthreads();
  }

  int r0l = wm * 64 + ((lane >> 4) * 4); // + fm*16 + i
  int c0l = wn * 64 + (lane & 15);       // + fn*16

  if (MODE == 0 || MODE == 2) {
    u16* Cb = (u16*)C + (size_t)z * sC;
#pragma unroll
    for (int fm = 0; fm < 4; ++fm)
#pragma unroll
      for (int fn = 0; fn < 4; ++fn)
#pragma unroll
        for (int i = 0; i < 4; ++i) {
          size_t r = (size_t)tm * 128 + r0l + fm * 16 + i;
          size_t c = (size_t)tn * 128 + c0l + fn * 16;
          Cb[r * N + c] = f2bf(acc[fm][fn][i]);
        }
  } else if (MODE == 1) {
    u16* Vt = (u16*)C;
#pragma unroll
    for (int fm = 0; fm < 4; ++fm)
#pragma unroll
      for (int fn = 0; fn < 4; ++fn) {
        int rg = tm * 128 + r0l + fm * 16; // global m row, multiple of 4
        int bb = rg >> 11, s0 = rg & 2047;
        int e = tn * 128 + c0l + fn * 16;
        u16x4 o = {f2bf(acc[fm][fn][0]), f2bf(acc[fm][fn][1]),
                   f2bf(acc[fm][fn][2]), f2bf(acc[fm][fn][3])};
        *(u16x4*)(Vt + (size_t)bb * 2097152 + (size_t)e * 2048 + s0) = o;
      }
  } else { // MODE 3
    float* Co = (float*)C + (size_t)z * sC;
#pragma unroll
    for (int fm = 0; fm < 4; ++fm)
#pragma unroll
      for (int fn = 0; fn < 4; ++fn)
#pragma unroll
        for (int i = 0; i < 4; ++i) {
          size_t r = (size_t)tm * 128 + r0l + fm * 16 + i;
          size_t c = (size_t)tn * 128 + c0l + fn * 16;
          Co[r * N + c] = acc[fm][fn][i];
        }
  }
}

// ---------------- causal row softmax over bf16 scores, in place ----------------
__global__ __launch_bounds__(256) void softmax_causal_kernel(u16* __restrict__ P) {
  int wid = threadIdx.x >> 6, lane = threadIdx.x & 63;
  int row = blockIdx.x * 4 + wid; // 0..8191
  int b = row >> 11, q = row & 2047;
  u16* rp = P + ((size_t)b * S_ + q) * S_;

  float vals[32];
  float m = -1e30f;
#pragma unroll
  for (int it = 0; it < 16; ++it) {
    int s0 = it * 128 + lane * 2;
    u32 u = *(const u32*)(rp + s0);
    float v0 = bf2f((u16)u) * SCALE_;
    float v1 = bf2f((u16)(u >> 16)) * SCALE_;
    v0 = (s0 <= q) ? v0 : -1e30f;
    v1 = (s0 + 1 <= q) ? v1 : -1e30f;
    vals[2 * it] = v0;
    vals[2 * it + 1] = v1;
    m = fmaxf(m, fmaxf(v0, v1));
  }
#pragma unroll
  for (int off = 32; off; off >>= 1) m = fmaxf(m, __shfl_xor(m, off, 64));

  float l = 0.f;
#pragma unroll
  for (int it = 0; it < 32; ++it) {
    vals[it] = __expf(vals[it] - m);
    l += vals[it];
  }
#pragma unroll
  for (int off = 32; off; off >>= 1) l += __shfl_xor(l, off, 64);
  float inv = 1.0f / l;

#pragma unroll
  for (int it = 0; it < 16; ++it) {
    int s0 = it * 128 + lane * 2;
    u32 o = (u32)f2bf(vals[2 * it] * inv) | ((u32)f2bf(vals[2 * it + 1] * inv) << 16);
    *(u32*)(rp + s0) = o;
  }
}

extern "C" void kernel_launch(void* const* d_in, const int* in_sizes, int n_in,
                              void* d_out, int out_size, void* d_ws, size_t ws_size,
                              hipStream_t stream) {
  const float* x = (const float*)d_in[0];
  const float* Wq = (const float*)d_in[1];
  const float* Wk = (const float*)d_in[2];
  const float* Wv = (const float*)d_in[3];
  float* out = (float*)d_out;

  u16* ws = (u16*)d_ws;
  u16* Xb = ws;                  // [8192][1024] bf16
  u16* Qb = ws + 8388608;        // [4][2048][1024]
  u16* Kb = ws + 16777216;       // [4][2048][1024]
  u16* Vt = ws + 25165824;       // [4][1024][2048]  (e-major)
  u16* Pm = ws + 33554432;       // [4][2048][2048]
  u16* Wqt = ws + 50331648;      // [1024][1024]
  u16* Wkt = Wqt + 1048576;
  u16* Wvt = Wkt + 1048576;

  cvt_x_kernel<<<8192, 256, 0, stream>>>(x, Xb);
  transpose_w_kernel<<<dim3(32, 32), dim3(32, 8), 0, stream>>>(Wq, Wqt);
  transpose_w_kernel<<<dim3(32, 32), dim3(32, 8), 0, stream>>>(Wk, Wkt);
  transpose_w_kernel<<<dim3(32, 32), dim3(32, 8), 0, stream>>>(Wv, Wvt);

  // projections: M=8192, N=1024, K=1024
  gemm_nt<0><<<dim3(64, 8, 1), 256, 0, stream>>>(Xb, Wqt, Qb, 1024, 1024, 0, 0, 0);
  gemm_nt<0><<<dim3(64, 8, 1), 256, 0, stream>>>(Xb, Wkt, Kb, 1024, 1024, 0, 0, 0);
  gemm_nt<1><<<dim3(64, 8, 1), 256, 0, stream>>>(Xb, Wvt, Vt, 1024, 1024, 0, 0, 0);

  // scores: per batch M=N=2048, K=1024, causal tile skip
  gemm_nt<2><<<dim3(16, 16, 4), 256, 0, stream>>>(Qb, Kb, Pm, 1024, 2048,
                                                  (long)2048 * 1024, (long)2048 * 1024,
                                                  (long)2048 * 2048);

  softmax_causal_kernel<<<2048, 256, 0, stream>>>(Pm);

  // PV: per batch M=2048, N=1024, K=2048 (causally truncated)
  gemm_nt<3><<<dim3(16, 8, 4), 256, 0, stream>>>(Pm, Vt, out, 2048, 1024,
                                                 (long)2048 * 2048, (long)1024 * 2048,
                                                 (long)2048 * 1024);
}

// Round 2
// 199.101 us; speedup vs baseline: 1.0170x; 1.0170x over previous
//
#include <hip/hip_runtime.h>

typedef unsigned short u16;
typedef unsigned int u32;
typedef __attribute__((ext_vector_type(8))) __bf16 bf16x8;
typedef __attribute__((ext_vector_type(4))) float f32x4;
typedef __attribute__((ext_vector_type(4))) u16 u16x4;

#define DEVFN static __device__ __forceinline__

constexpr int S_ = 2048;
constexpr int D_ = 1024;
constexpr float SCALE_ = 0.03125f; // 1/sqrt(1024)

DEVFN u16 f2bf(float f) {
  u32 u = __builtin_bit_cast(u32, f);
  return (u16)((u + 0x7fffu + ((u >> 16) & 1u)) >> 16);
}
DEVFN float bf2f(u16 h) {
  u32 u = ((u32)h) << 16;
  return __builtin_bit_cast(float, u);
}
DEVFN void gld16(const u16* g, u16* l) {
  __builtin_amdgcn_global_load_lds(
      (const __attribute__((address_space(1))) u32*)g,
      (__attribute__((address_space(3))) u32*)l, 16, 0, 0);
}

// ---------------- x fp32 -> bf16 ----------------
__global__ __launch_bounds__(256) void cvt_x_kernel(const float* __restrict__ x,
                                                    u16* __restrict__ xb) {
  int i = blockIdx.x * 256 + threadIdx.x;
  float4 v = ((const float4*)x)[i];
  u16x4 o = {f2bf(v.x), f2bf(v.y), f2bf(v.z), f2bf(v.w)};
  ((u16x4*)xb)[i] = o;
}

// ---------------- W [K][N] fp32 -> Wt [N][K] bf16 ----------------
__global__ __launch_bounds__(256) void transpose_w_kernel(const float* __restrict__ W,
                                                          u16* __restrict__ Wt) {
  __shared__ float t[32][33];
  int tx = threadIdx.x, ty = threadIdx.y; // block (32,8)
  int n0 = blockIdx.x * 32, k0 = blockIdx.y * 32;
#pragma unroll
  for (int i = 0; i < 4; ++i)
    t[ty + i * 8][tx] = W[(size_t)(k0 + ty + i * 8) * D_ + n0 + tx];
  __syncthreads();
#pragma unroll
  for (int i = 0; i < 4; ++i)
    Wt[(size_t)(n0 + ty + i * 8) * D_ + k0 + tx] = f2bf(t[tx][ty + i * 8]);
}

// ---------------- 256x256 8-wave NT GEMM, BK=32, 4-deep counted-vmcnt pipeline ----
// MODE 0: A=Xb[8192][1024], Bt=Wcat[3072][1024]; out: Q->O0, K->O1, V->O2 (transposed Vt[b][e][s])
// MODE 2: per-batch scores: A=Qb, Bt=Kb (K=1024, N=2048), bf16 out O0, causal tile skip
// MODE 3: per-batch PV: A=Pm[2048][2048], Bt=Vt[1024][2048], fp32 out OF, causal K trunc
template <int MODE>
__global__ __launch_bounds__(512, 2) void gemm256(const u16* __restrict__ A,
                                                  const u16* __restrict__ Bt,
                                                  u16* __restrict__ O0,
                                                  u16* __restrict__ O1,
                                                  u16* __restrict__ O2,
                                                  float* __restrict__ OF) {
  int tm = blockIdx.x, tn = blockIdx.y, z = blockIdx.z;
  if (MODE == 2 && tn > tm) return;
  constexpr int LDA = (MODE == 3) ? 2048 : 1024;
  constexpr int LDB = (MODE == 3) ? 2048 : 1024;
  const int NKT = (MODE == 3) ? (tm + 1) * 8 : 32;

  __shared__ u16 ls[4][2][8192]; // 4 ring buffers x {A,B} x 16KB = 128 KiB

  int tid = threadIdx.x;
  int lane = tid & 63, wid = tid >> 6;
  int wm = wid >> 2, wn = wid & 3; // 2(M) x 4(N) waves

  const u16* Ab = A +
      (MODE == 2 ? (size_t)z * (2048 * 1024)
                 : (MODE == 3 ? (size_t)z * (2048 * 2048) : (size_t)0)) +
      (size_t)tm * 256 * LDA;
  const u16* Bb = Bt +
      (MODE == 2 ? (size_t)z * (2048 * 1024)
                 : (MODE == 3 ? (size_t)z * (1024 * 2048) : (size_t)0)) +
      (size_t)tn * 256 * LDB;

  int srow = tid >> 2;      // staging row 0..127
  int scol = (tid & 3) * 8; // staging k-offset (elements)

#define STAGE(bf, kt)                                                           \
  do {                                                                          \
    int k0_ = (kt) * 32;                                                        \
    gld16(Ab + (size_t)srow * LDA + k0_ + scol, &ls[bf][0][0] + tid * 8);       \
    gld16(Ab + (size_t)(srow + 128) * LDA + k0_ + scol,                         \
          &ls[bf][0][0] + 4096 + tid * 8);                                      \
    gld16(Bb + (size_t)srow * LDB + k0_ + scol, &ls[bf][1][0] + tid * 8);       \
    gld16(Bb + (size_t)(srow + 128) * LDB + k0_ + scol,                         \
          &ls[bf][1][0] + 4096 + tid * 8);                                      \
  } while (0)

  const int aoff = (wm * 128 + (lane & 15)) * 32 + (lane >> 4) * 8;
  const int boff = (wn * 64 + (lane & 15)) * 32 + (lane >> 4) * 8;

  f32x4 acc[8][4] = {};

  // prologue: 3 K-tiles in flight
  STAGE(0, 0);
  STAGE(1, 1);
  STAGE(2, 2);

  // Per K-tile: wait own loads for tile t (counted), barrier publishes everyone's
  // slices AND all reads of tile t-1, then stage t+3 into the freed buffer.
#define KSTEP(t, W)                                                             \
  do {                                                                          \
    asm volatile("s_waitcnt vmcnt(%0)" ::"n"(W) : "memory");                    \
    __builtin_amdgcn_s_barrier();                                               \
    __builtin_amdgcn_sched_barrier(0);                                          \
    if ((t) + 3 < NKT) STAGE(((t) + 3) & 3, (t) + 3);                           \
    const u16* la_ = &ls[(t) & 3][0][0] + aoff;                                 \
    const u16* lb_ = &ls[(t) & 3][1][0] + boff;                                 \
    bf16x8 aF[8], bF[4];                                                        \
    _Pragma("unroll") for (int f = 0; f < 8; ++f)                               \
        aF[f] = *(const bf16x8*)(la_ + f * 512);                                \
    _Pragma("unroll") for (int f = 0; f < 4; ++f)                               \
        bF[f] = *(const bf16x8*)(lb_ + f * 512);                                \
    __builtin_amdgcn_s_setprio(1);                                              \
    _Pragma("unroll") for (int fm = 0; fm < 8; ++fm)                            \
        _Pragma("unroll") for (int fn = 0; fn < 4; ++fn)                        \
            acc[fm][fn] = __builtin_amdgcn_mfma_f32_16x16x32_bf16(              \
                aF[fm], bF[fn], acc[fm][fn], 0, 0, 0);                          \
    __builtin_amdgcn_s_setprio(0);                                              \
  } while (0)

  for (int t = 0; t < NKT - 2; ++t) KSTEP(t, 8);
  KSTEP(NKT - 2, 4);
  KSTEP(NKT - 1, 0);

#undef KSTEP
#undef STAGE

  // ---- epilogue ----
  int r0 = tm * 256 + wm * 128 + (lane >> 4) * 4;
  int c0 = tn * 256 + wn * 64 + (lane & 15);

  if (MODE == 0) {
    if (tn < 8) {
      u16* O = (tn < 4) ? O0 : O1;
      int cb = (tn < 4) ? 0 : 1024;
#pragma unroll
      for (int fm = 0; fm < 8; ++fm)
#pragma unroll
        for (int fn = 0; fn < 4; ++fn)
#pragma unroll
          for (int i = 0; i < 4; ++i)
            O[(size_t)(r0 + fm * 16 + i) * 1024 + (c0 + fn * 16 - cb)] =
                f2bf(acc[fm][fn][i]);
    } else {
#pragma unroll
      for (int fm = 0; fm < 8; ++fm)
#pragma unroll
        for (int fn = 0; fn < 4; ++fn) {
          int r = r0 + fm * 16;
          int bb = r >> 11, s0 = r & 2047;
          int e = c0 + fn * 16 - 2048;
          u16x4 o = {f2bf(acc[fm][fn][0]), f2bf(acc[fm][fn][1]),
                     f2bf(acc[fm][fn][2]), f2bf(acc[fm][fn][3])};
          *(u16x4*)(O2 + (size_t)bb * 2097152 + (size_t)e * 2048 + s0) = o;
        }
    }
  } else if (MODE == 2) {
    u16* P = O0 + (size_t)z * 4194304;
#pragma unroll
    for (int fm = 0; fm < 8; ++fm)
#pragma unroll
      for (int fn = 0; fn < 4; ++fn)
#pragma unroll
        for (int i = 0; i < 4; ++i)
          P[(size_t)(r0 + fm * 16 + i) * 2048 + (c0 + fn * 16)] =
              f2bf(acc[fm][fn][i]);
  } else {
    float* Ob = OF + (size_t)z * 2097152;
#pragma unroll
    for (int fm = 0; fm < 8; ++fm)
#pragma unroll
      for (int fn = 0; fn < 4; ++fn)
#pragma unroll
        for (int i = 0; i < 4; ++i)
          Ob[(size_t)(r0 + fm * 16 + i) * 1024 + (c0 + fn * 16)] = acc[fm][fn][i];
  }
}

// ---------------- causal row softmax over bf16 scores, in place ----------------
__global__ __launch_bounds__(256) void softmax_causal_kernel(u16* __restrict__ P) {
  int wid = threadIdx.x >> 6, lane = threadIdx.x & 63;
  int row = blockIdx.x * 4 + wid; // 0..8191
  int b = row >> 11, q = row & 2047;
  u16* rp = P + ((size_t)b * S_ + q) * S_;

  float vals[32];
  float m = -1e30f;
#pragma unroll
  for (int it = 0; it < 16; ++it) {
    int s0 = it * 128 + lane * 2;
    u32 u = *(const u32*)(rp + s0);
    float v0 = bf2f((u16)u) * SCALE_;
    float v1 = bf2f((u16)(u >> 16)) * SCALE_;
    v0 = (s0 <= q) ? v0 : -1e30f;
    v1 = (s0 + 1 <= q) ? v1 : -1e30f;
    vals[2 * it] = v0;
    vals[2 * it + 1] = v1;
    m = fmaxf(m, fmaxf(v0, v1));
  }
#pragma unroll
  for (int off = 32; off; off >>= 1) m = fmaxf(m, __shfl_xor(m, off, 64));

  float l = 0.f;
#pragma unroll
  for (int it = 0; it < 32; ++it) {
    vals[it] = __expf(vals[it] - m);
    l += vals[it];
  }
#pragma unroll
  for (int off = 32; off; off >>= 1) l += __shfl_xor(l, off, 64);
  float inv = 1.0f / l;

#pragma unroll
  for (int it = 0; it < 16; ++it) {
    int s0 = it * 128 + lane * 2;
    u32 o = (u32)f2bf(vals[2 * it] * inv) | ((u32)f2bf(vals[2 * it + 1] * inv) << 16);
    *(u32*)(rp + s0) = o;
  }
}

extern "C" void kernel_launch(void* const* d_in, const int* in_sizes, int n_in,
                              void* d_out, int out_size, void* d_ws, size_t ws_size,
                              hipStream_t stream) {
  const float* x = (const float*)d_in[0];
  const float* Wq = (const float*)d_in[1];
  const float* Wk = (const float*)d_in[2];
  const float* Wv = (const float*)d_in[3];
  float* out = (float*)d_out;

  u16* ws = (u16*)d_ws;
  u16* Xb = ws;              // [8192][1024]
  u16* Qb = ws + 8388608;    // [4][2048][1024]
  u16* Kb = ws + 16777216;   // [4][2048][1024]
  u16* Vt = ws + 25165824;   // [4][1024][2048] (e-major)
  u16* Pm = ws + 33554432;   // [4][2048][2048]
  u16* Wcat = ws + 50331648; // [3072][1024]: Wq^T | Wk^T | Wv^T

  cvt_x_kernel<<<8192, 256, 0, stream>>>(x, Xb);
  transpose_w_kernel<<<dim3(32, 32), dim3(32, 8), 0, stream>>>(Wq, Wcat);
  transpose_w_kernel<<<dim3(32, 32), dim3(32, 8), 0, stream>>>(Wk, Wcat + 1048576);
  transpose_w_kernel<<<dim3(32, 32), dim3(32, 8), 0, stream>>>(Wv, Wcat + 2097152);

  // fused QKV projection: M=8192, N=3072, K=1024
  gemm256<0><<<dim3(32, 12, 1), 512, 0, stream>>>(Xb, Wcat, Qb, Kb, Vt, nullptr);

  // scores: per batch M=N=2048, K=1024, causal tile skip
  gemm256<2><<<dim3(8, 8, 4), 512, 0, stream>>>(Qb, Kb, Pm, nullptr, nullptr, nullptr);

  softmax_causal_kernel<<<2048, 256, 0, stream>>>(Pm);

  // PV: per batch M=2048, N=1024, K=2048 (causally truncated)
  gemm256<3><<<dim3(8, 4, 4), 512, 0, stream>>>(Pm, Vt, nullptr, nullptr, nullptr, out);
}

// Round 3
// 187.757 us; speedup vs baseline: 1.0785x; 1.0604x over previous
//
#include <hip/hip_runtime.h>

typedef unsigned short u16;
typedef unsigned int u32;
typedef __attribute__((ext_vector_type(8))) __bf16 bf16x8;
typedef __attribute__((ext_vector_type(4))) float f32x4;
typedef __attribute__((ext_vector_type(4))) u16 u16x4;

#define DEVFN static __device__ __forceinline__

constexpr int S_ = 2048;
constexpr int D_ = 1024;
constexpr float SCALE_ = 0.03125f; // 1/sqrt(1024)

DEVFN u16 f2bf(float f) {
  u32 u = __builtin_bit_cast(u32, f);
  return (u16)((u + 0x7fffu + ((u >> 16) & 1u)) >> 16);
}
DEVFN float bf2f(u16 h) {
  u32 u = ((u32)h) << 16;
  return __builtin_bit_cast(float, u);
}
DEVFN void gld16(const u16* g, u16* l) {
  __builtin_amdgcn_global_load_lds(
      (const __attribute__((address_space(1))) u32*)g,
      (__attribute__((address_space(3))) u32*)l, 16, 0, 0);
}

// ---------------- x fp32 -> bf16 ----------------
__global__ __launch_bounds__(256) void cvt_x_kernel(const float* __restrict__ x,
                                                    u16* __restrict__ xb) {
  int i = blockIdx.x * 256 + threadIdx.x;
  float4 v = ((const float4*)x)[i];
  u16x4 o = {f2bf(v.x), f2bf(v.y), f2bf(v.z), f2bf(v.w)};
  ((u16x4*)xb)[i] = o;
}

// ---------------- W [K][N] fp32 -> Wt [N][K] bf16 ----------------
__global__ __launch_bounds__(256) void transpose_w_kernel(const float* __restrict__ W,
                                                          u16* __restrict__ Wt) {
  __shared__ float t[32][33];
  int tx = threadIdx.x, ty = threadIdx.y; // block (32,8)
  int n0 = blockIdx.x * 32, k0 = blockIdx.y * 32;
#pragma unroll
  for (int i = 0; i < 4; ++i)
    t[ty + i * 8][tx] = W[(size_t)(k0 + ty + i * 8) * D_ + n0 + tx];
  __syncthreads();
#pragma unroll
  for (int i = 0; i < 4; ++i)
    Wt[(size_t)(n0 + ty + i * 8) * D_ + k0 + tx] = f2bf(t[tx][ty + i * 8]);
}

// ---------------- 256x256 8-wave NT GEMM, BK=32, 4-deep counted-vmcnt pipeline ----
// LDS layout per operand tile: 1024 16B-blocks, logical block b = row*4 + kchunk
// stored at block s(b) = b ^ ((b>>3)&7)  (involution; conflict-free ds_read_b128).
// MODE 0: A=Xb[8192][1024], Bt=Wcat[3072][1024]; out: Q->O0, K->O1, V->O2 (Vt[b][e][s])
// MODE 2: per-batch scores: A=Qb, Bt=Kb (K=1024, N=2048), bf16 out O0, causal tile skip
// MODE 3: per-batch PV: A=Pm[2048][2048], Bt=Vt[1024][2048], fp32 out OF, causal K trunc
template <int MODE>
__global__ __launch_bounds__(512, 2) void gemm256(const u16* __restrict__ A,
                                                  const u16* __restrict__ Bt,
                                                  u16* __restrict__ O0,
                                                  u16* __restrict__ O1,
                                                  u16* __restrict__ O2,
                                                  float* __restrict__ OF) {
  int tm = blockIdx.x, tn = blockIdx.y, z = blockIdx.z;
  if (MODE == 2 && tn > tm) return;
  constexpr int LDA = (MODE == 3) ? 2048 : 1024;
  constexpr int LDB = (MODE == 3) ? 2048 : 1024;
  const int NKT = (MODE == 3) ? (tm + 1) * 8 : 32;

  __shared__ u16 ls[4][2][8192]; // 4 ring buffers x {A,B} x 16KB = 128 KiB

  int tid = threadIdx.x;
  int lane = tid & 63, wid = tid >> 6;
  int wm = wid >> 2, wn = wid & 3; // 2(M) x 4(N) waves

  const u16* Ab = A +
      (MODE == 2 ? (size_t)z * (2048 * 1024)
                 : (MODE == 3 ? (size_t)z * (2048 * 2048) : (size_t)0)) +
      (size_t)tm * 256 * LDA;
  const u16* Bb = Bt +
      (MODE == 2 ? (size_t)z * (2048 * 1024)
                 : (MODE == 3 ? (size_t)z * (1024 * 2048) : (size_t)0)) +
      (size_t)tn * 256 * LDB;

  // staging: thread tid fills LDS block tid (and tid+512); global source block is
  // the swizzle-inverse (= same XOR, involution) of the dest block.
  int gsw = tid ^ ((tid >> 3) & 7);
  int srow = gsw >> 2;        // 0..127
  int scol = (gsw & 3) * 8;   // k-offset (elements)

#define STAGE(bf, kt)                                                           \
  do {                                                                          \
    int k0_ = (kt) * 32;                                                        \
    gld16(Ab + (size_t)srow * LDA + k0_ + scol, &ls[bf][0][0] + tid * 8);       \
    gld16(Ab + (size_t)(srow + 128) * LDA + k0_ + scol,                         \
          &ls[bf][0][0] + 4096 + tid * 8);                                      \
    gld16(Bb + (size_t)srow * LDB + k0_ + scol, &ls[bf][1][0] + tid * 8);       \
    gld16(Bb + (size_t)(srow + 128) * LDB + k0_ + scol,                         \
          &ls[bf][1][0] + 4096 + tid * 8);                                      \
  } while (0)

  // fragment read offsets (swizzled); +f*16 rows => +f*512 elems (swizzle invariant)
  const int kg_ = lane >> 4;
  const int arow = wm * 128 + (lane & 15);
  const int brow = wn * 64 + (lane & 15);
  const int aoff = ((arow * 4 + kg_) ^ ((arow >> 1) & 7)) * 8;
  const int boff = ((brow * 4 + kg_) ^ ((brow >> 1) & 7)) * 8;

  f32x4 acc[8][4] = {};

  // prologue: 3 K-tiles in flight
  STAGE(0, 0);
  STAGE(1, 1);
  STAGE(2, 2);

#define KSTEP(t, W)                                                             \
  do {                                                                          \
    asm volatile("s_waitcnt vmcnt(%0)" ::"n"(W) : "memory");                    \
    __builtin_amdgcn_s_barrier();                                               \
    __builtin_amdgcn_sched_barrier(0);                                          \
    if ((t) + 3 < NKT) STAGE(((t) + 3) & 3, (t) + 3);                           \
    const u16* la_ = &ls[(t) & 3][0][0] + aoff;                                 \
    const u16* lb_ = &ls[(t) & 3][1][0] + boff;                                 \
    bf16x8 aF[8], bF[4];                                                        \
    _Pragma("unroll") for (int f = 0; f < 8; ++f)                               \
        aF[f] = *(const bf16x8*)(la_ + f * 512);                                \
    _Pragma("unroll") for (int f = 0; f < 4; ++f)                               \
        bF[f] = *(const bf16x8*)(lb_ + f * 512);                                \
    __builtin_amdgcn_s_setprio(1);                                              \
    _Pragma("unroll") for (int fm = 0; fm < 8; ++fm)                            \
        _Pragma("unroll") for (int fn = 0; fn < 4; ++fn)                        \
            acc[fm][fn] = __builtin_amdgcn_mfma_f32_16x16x32_bf16(              \
                aF[fm], bF[fn], acc[fm][fn], 0, 0, 0);                          \
    __builtin_amdgcn_s_setprio(0);                                              \
  } while (0)

  for (int t = 0; t < NKT - 2; ++t) KSTEP(t, 8);
  KSTEP(NKT - 2, 4);
  KSTEP(NKT - 1, 0);

#undef KSTEP
#undef STAGE

  // ---- epilogue ----
  int r0 = tm * 256 + wm * 128 + (lane >> 4) * 4;
  int c0 = tn * 256 + wn * 64 + (lane & 15);

  if (MODE == 0) {
    if (tn < 8) {
      u16* O = (tn < 4) ? O0 : O1;
      int cb = (tn < 4) ? 0 : 1024;
#pragma unroll
      for (int fm = 0; fm < 8; ++fm)
#pragma unroll
        for (int fn = 0; fn < 4; ++fn)
#pragma unroll
          for (int i = 0; i < 4; ++i)
            O[(size_t)(r0 + fm * 16 + i) * 1024 + (c0 + fn * 16 - cb)] =
                f2bf(acc[fm][fn][i]);
    } else {
#pragma unroll
      for (int fm = 0; fm < 8; ++fm)
#pragma unroll
        for (int fn = 0; fn < 4; ++fn) {
          int r = r0 + fm * 16;
          int bb = r >> 11, s0 = r & 2047;
          int e = c0 + fn * 16 - 2048;
          u16x4 o = {f2bf(acc[fm][fn][0]), f2bf(acc[fm][fn][1]),
                     f2bf(acc[fm][fn][2]), f2bf(acc[fm][fn][3])};
          *(u16x4*)(O2 + (size_t)bb * 2097152 + (size_t)e * 2048 + s0) = o;
        }
    }
  } else if (MODE == 2) {
    u16* P = O0 + (size_t)z * 4194304;
#pragma unroll
    for (int fm = 0; fm < 8; ++fm)
#pragma unroll
      for (int fn = 0; fn < 4; ++fn)
#pragma unroll
        for (int i = 0; i < 4; ++i)
          P[(size_t)(r0 + fm * 16 + i) * 2048 + (c0 + fn * 16)] =
              f2bf(acc[fm][fn][i]);
  } else {
    float* Ob = OF + (size_t)z * 2097152;
#pragma unroll
    for (int fm = 0; fm < 8; ++fm)
#pragma unroll
      for (int fn = 0; fn < 4; ++fn)
#pragma unroll
        for (int i = 0; i < 4; ++i)
          Ob[(size_t)(r0 + fm * 16 + i) * 1024 + (c0 + fn * 16)] = acc[fm][fn][i];
  }
}

// ---------------- causal row softmax over bf16 scores, in place ----------------
__global__ __launch_bounds__(256) void softmax_causal_kernel(u16* __restrict__ P) {
  int wid = threadIdx.x >> 6, lane = threadIdx.x & 63;
  int row = blockIdx.x * 4 + wid; // 0..8191
  int b = row >> 11, q = row & 2047;
  u16* rp = P + ((size_t)b * S_ + q) * S_;

  float vals[32];
  float m = -1e30f;
#pragma unroll
  for (int it = 0; it < 16; ++it) {
    int s0 = it * 128 + lane * 2;
    u32 u = *(const u32*)(rp + s0);
    float v0 = bf2f((u16)u) * SCALE_;
    float v1 = bf2f((u16)(u >> 16)) * SCALE_;
    v0 = (s0 <= q) ? v0 : -1e30f;
    v1 = (s0 + 1 <= q) ? v1 : -1e30f;
    vals[2 * it] = v0;
    vals[2 * it + 1] = v1;
    m = fmaxf(m, fmaxf(v0, v1));
  }
#pragma unroll
  for (int off = 32; off; off >>= 1) m = fmaxf(m, __shfl_xor(m, off, 64));

  float l = 0.f;
#pragma unroll
  for (int it = 0; it < 32; ++it) {
    vals[it] = __expf(vals[it] - m);
    l += vals[it];
  }
#pragma unroll
  for (int off = 32; off; off >>= 1) l += __shfl_xor(l, off, 64);
  float inv = 1.0f / l;

#pragma unroll
  for (int it = 0; it < 16; ++it) {
    int s0 = it * 128 + lane * 2;
    u32 o = (u32)f2bf(vals[2 * it] * inv) | ((u32)f2bf(vals[2 * it + 1] * inv) << 16);
    *(u32*)(rp + s0) = o;
  }
}

extern "C" void kernel_launch(void* const* d_in, const int* in_sizes, int n_in,
                              void* d_out, int out_size, void* d_ws, size_t ws_size,
                              hipStream_t stream) {
  const float* x = (const float*)d_in[0];
  const float* Wq = (const float*)d_in[1];
  const float* Wk = (const float*)d_in[2];
  const float* Wv = (const float*)d_in[3];
  float* out = (float*)d_out;

  u16* ws = (u16*)d_ws;
  u16* Xb = ws;              // [8192][1024]
  u16* Qb = ws + 8388608;    // [4][2048][1024]
  u16* Kb = ws + 16777216;   // [4][2048][1024]
  u16* Vt = ws + 25165824;   // [4][1024][2048] (e-major)
  u16* Pm = ws + 33554432;   // [4][2048][2048]
  u16* Wcat = ws + 50331648; // [3072][1024]: Wq^T | Wk^T | Wv^T

  cvt_x_kernel<<<8192, 256, 0, stream>>>(x, Xb);
  transpose_w_kernel<<<dim3(32, 32), dim3(32, 8), 0, stream>>>(Wq, Wcat);
  transpose_w_kernel<<<dim3(32, 32), dim3(32, 8), 0, stream>>>(Wk, Wcat + 1048576);
  transpose_w_kernel<<<dim3(32, 32), dim3(32, 8), 0, stream>>>(Wv, Wcat + 2097152);

  // fused QKV projection: M=8192, N=3072, K=1024
  gemm256<0><<<dim3(32, 12, 1), 512, 0, stream>>>(Xb, Wcat, Qb, Kb, Vt, nullptr);

  // scores: per batch M=N=2048, K=1024, causal tile skip
  gemm256<2><<<dim3(8, 8, 4), 512, 0, stream>>>(Qb, Kb, Pm, nullptr, nullptr, nullptr);

  softmax_causal_kernel<<<2048, 256, 0, stream>>>(Pm);

  // PV: per batch M=2048, N=1024, K=2048 (causally truncated)
  gemm256<3><<<dim3(8, 4, 4), 512, 0, stream>>>(Pm, Vt, nullptr, nullptr, nullptr, out);
}

// Round 4
// 157.487 us; speedup vs baseline: 1.2858x; 1.1922x over previous
//
#include <hip/hip_runtime.h>

typedef unsigned short u16;
typedef unsigned int u32;
typedef __attribute__((ext_vector_type(8))) __bf16 bf16x8;
typedef __attribute__((ext_vector_type(4))) float f32x4;
typedef __attribute__((ext_vector_type(4))) u16 u16x4;

#define DEVFN static __device__ __forceinline__

constexpr int S_ = 2048;
constexpr int D_ = 1024;
constexpr float SCALE_ = 0.03125f; // 1/sqrt(1024)

DEVFN u16 f2bf(float f) {
  u32 u = __builtin_bit_cast(u32, f);
  return (u16)((u + 0x7fffu + ((u >> 16) & 1u)) >> 16);
}
DEVFN float bf2f(u16 h) {
  u32 u = ((u32)h) << 16;
  return __builtin_bit_cast(float, u);
}
DEVFN void gld16(const u16* g, u16* l) {
  __builtin_amdgcn_global_load_lds(
      (const __attribute__((address_space(1))) u32*)g,
      (__attribute__((address_space(3))) u32*)l, 16, 0, 0);
}

// ---------------- x fp32 -> bf16 ----------------
__global__ __launch_bounds__(256) void cvt_x_kernel(const float* __restrict__ x,
                                                    u16* __restrict__ xb) {
  int i = blockIdx.x * 256 + threadIdx.x;
  float4 v = ((const float4*)x)[i];
  u16x4 o = {f2bf(v.x), f2bf(v.y), f2bf(v.z), f2bf(v.w)};
  ((u16x4*)xb)[i] = o;
}

// ---------------- W [K][N] fp32 -> Wt [N][K] bf16 ----------------
__global__ __launch_bounds__(256) void transpose_w_kernel(const float* __restrict__ W,
                                                          u16* __restrict__ Wt) {
  __shared__ float t[32][33];
  int tx = threadIdx.x, ty = threadIdx.y; // block (32,8)
  int n0 = blockIdx.x * 32, k0 = blockIdx.y * 32;
#pragma unroll
  for (int i = 0; i < 4; ++i)
    t[ty + i * 8][tx] = W[(size_t)(k0 + ty + i * 8) * D_ + n0 + tx];
  __syncthreads();
#pragma unroll
  for (int i = 0; i < 4; ++i)
    Wt[(size_t)(n0 + ty + i * 8) * D_ + k0 + tx] = f2bf(t[tx][ty + i * 8]);
}

// ---------------- 256x256 8-wave NT GEMM for the fused QKV projection ---------
// (unchanged from round 3: BK=32, 4-deep ring, counted vmcnt, swizzled LDS)
__global__ __launch_bounds__(512, 2) void gemm256(const u16* __restrict__ A,
                                                  const u16* __restrict__ Bt,
                                                  u16* __restrict__ O0,
                                                  u16* __restrict__ O1,
                                                  u16* __restrict__ O2) {
  int tm = blockIdx.x, tn = blockIdx.y;
  constexpr int LDA = 1024, LDB = 1024;
  const int NKT = 32;

  __shared__ u16 ls[4][2][8192]; // 4 ring buffers x {A,B} x 16KB = 128 KiB

  int tid = threadIdx.x;
  int lane = tid & 63, wid = tid >> 6;
  int wm = wid >> 2, wn = wid & 3; // 2(M) x 4(N) waves

  const u16* Ab = A + (size_t)tm * 256 * LDA;
  const u16* Bb = Bt + (size_t)tn * 256 * LDB;

  int gsw = tid ^ ((tid >> 3) & 7);
  int srow = gsw >> 2;      // 0..127
  int scol = (gsw & 3) * 8; // k-offset (elements)

#define STAGE(bf, kt)                                                           \
  do {                                                                          \
    int k0_ = (kt) * 32;                                                        \
    gld16(Ab + (size_t)srow * LDA + k0_ + scol, &ls[bf][0][0] + tid * 8);       \
    gld16(Ab + (size_t)(srow + 128) * LDA + k0_ + scol,                         \
          &ls[bf][0][0] + 4096 + tid * 8);                                      \
    gld16(Bb + (size_t)srow * LDB + k0_ + scol, &ls[bf][1][0] + tid * 8);       \
    gld16(Bb + (size_t)(srow + 128) * LDB + k0_ + scol,                         \
          &ls[bf][1][0] + 4096 + tid * 8);                                      \
  } while (0)

  const int kg_ = lane >> 4;
  const int arow = wm * 128 + (lane & 15);
  const int brow = wn * 64 + (lane & 15);
  const int aoff = ((arow * 4 + kg_) ^ ((arow >> 1) & 7)) * 8;
  const int boff = ((brow * 4 + kg_) ^ ((brow >> 1) & 7)) * 8;

  f32x4 acc[8][4] = {};

  STAGE(0, 0);
  STAGE(1, 1);
  STAGE(2, 2);

#define KSTEP(t, W)                                                             \
  do {                                                                          \
    asm volatile("s_waitcnt vmcnt(%0)" ::"n"(W) : "memory");                    \
    __builtin_amdgcn_s_barrier();                                               \
    __builtin_amdgcn_sched_barrier(0);                                          \
    if ((t) + 3 < NKT) STAGE(((t) + 3) & 3, (t) + 3);                           \
    const u16* la_ = &ls[(t) & 3][0][0] + aoff;                                 \
    const u16* lb_ = &ls[(t) & 3][1][0] + boff;                                 \
    bf16x8 aF[8], bF[4];                                                        \
    _Pragma("unroll") for (int f = 0; f < 8; ++f)                               \
        aF[f] = *(const bf16x8*)(la_ + f * 512);                                \
    _Pragma("unroll") for (int f = 0; f < 4; ++f)                               \
        bF[f] = *(const bf16x8*)(lb_ + f * 512);                                \
    __builtin_amdgcn_s_setprio(1);                                              \
    _Pragma("unroll") for (int fm = 0; fm < 8; ++fm)                            \
        _Pragma("unroll") for (int fn = 0; fn < 4; ++fn)                        \
            acc[fm][fn] = __builtin_amdgcn_mfma_f32_16x16x32_bf16(              \
                aF[fm], bF[fn], acc[fm][fn], 0, 0, 0);                          \
    __builtin_amdgcn_s_setprio(0);                                              \
  } while (0)

  for (int t = 0; t < NKT - 2; ++t) KSTEP(t, 8);
  KSTEP(NKT - 2, 4);
  KSTEP(NKT - 1, 0);

#undef KSTEP
#undef STAGE

  int r0 = tm * 256 + wm * 128 + (lane >> 4) * 4;
  int c0 = tn * 256 + wn * 64 + (lane & 15);

  if (tn < 8) {
    u16* O = (tn < 4) ? O0 : O1;
    int cb = (tn < 4) ? 0 : 1024;
#pragma unroll
    for (int fm = 0; fm < 8; ++fm)
#pragma unroll
      for (int fn = 0; fn < 4; ++fn)
#pragma unroll
        for (int i = 0; i < 4; ++i)
          O[(size_t)(r0 + fm * 16 + i) * 1024 + (c0 + fn * 16 - cb)] =
              f2bf(acc[fm][fn][i]);
  } else {
#pragma unroll
    for (int fm = 0; fm < 8; ++fm)
#pragma unroll
      for (int fn = 0; fn < 4; ++fn) {
        int r = r0 + fm * 16;
        int bb = r >> 11, s0 = r & 2047;
        int e = c0 + fn * 16 - 2048;
        u16x4 o = {f2bf(acc[fm][fn][0]), f2bf(acc[fm][fn][1]),
                   f2bf(acc[fm][fn][2]), f2bf(acc[fm][fn][3])};
        *(u16x4*)(O2 + (size_t)bb * 2097152 + (size_t)e * 2048 + s0) = o;
      }
  }
}

// ---------------- 128x128 4-wave NT GEMM, BK=64, 2-deep counted-vmcnt ---------
// LDS per operand tile: 128 rows x 8 chunks(16B); block b=row*8+chunk stored at
// b ^ ((b>>3)&7). 64 KiB total -> 2 blocks/CU.
// MODE 2: scores  A=Qb, Bt=Kb (LD=1024, K=1024), bf16 out, causal tile skip
// MODE 3: PV      A=Pm, Bt=Vt (LD=2048), fp32 out, K=(tm+1)*128, tm remapped
template <int MODE>
__global__ __launch_bounds__(256, 2) void gemm128(const u16* __restrict__ A,
                                                  const u16* __restrict__ Bt,
                                                  u16* __restrict__ OB,
                                                  float* __restrict__ OF) {
  int tmx = blockIdx.x, tn = blockIdx.y, z = blockIdx.z;
  // PV: pair big-K and small-K blocks so adjacent blocks balance per CU.
  int tm = (MODE == 3) ? ((tmx & 1) ? 15 - (tmx >> 1) : (tmx >> 1)) : tmx;
  if (MODE == 2 && tn > tm) return;
  constexpr int LDA = (MODE == 3) ? 2048 : 1024;
  constexpr int LDB = (MODE == 3) ? 2048 : 1024;
  const int NKT = (MODE == 3) ? (tm + 1) * 2 : 16;

  __shared__ u16 ls[2][2][8192]; // 2 buffers x {A,B} x 16KB = 64 KiB

  int tid = threadIdx.x;
  int lane = tid & 63, wid = tid >> 6;
  int wm = wid >> 1, wn = wid & 1; // 2(M) x 2(N) waves

  const u16* Ab = A + (size_t)z * ((MODE == 3) ? 2048 * 2048 : 2048 * 1024) +
                  (size_t)tm * 128 * LDA;
  const u16* Bb = Bt + (size_t)z * ((MODE == 3) ? 1024 * 2048 : 2048 * 1024) +
                  (size_t)tn * 128 * LDB;

  int gsw = tid ^ ((tid >> 3) & 7);
  int srow0 = gsw >> 3;     // 0..31
  int scol = (gsw & 7) * 8; // k-offset (elements)

#define STG(bf, kt)                                                             \
  do {                                                                          \
    int k0_ = (kt) * 64;                                                        \
    _Pragma("unroll") for (int j = 0; j < 4; ++j)                               \
        gld16(Ab + (size_t)(j * 32 + srow0) * LDA + k0_ + scol,                 \
              &ls[bf][0][0] + (j * 256 + tid) * 8);                             \
    _Pragma("unroll") for (int j = 0; j < 4; ++j)                               \
        gld16(Bb + (size_t)(j * 32 + srow0) * LDB + k0_ + scol,                 \
              &ls[bf][1][0] + (j * 256 + tid) * 8);                             \
  } while (0)

  int ar = wm * 64 + (lane & 15);
  int br = wn * 64 + (lane & 15);
  int ac = lane >> 4; // chunk 0..3 (ks=0), +4 for ks=1
  const int aoff0 = ar * 64 + ((ac ^ (ar & 7)) * 8);
  const int aoff1 = ar * 64 + (((ac + 4) ^ (ar & 7)) * 8);
  const int boff0 = br * 64 + ((ac ^ (br & 7)) * 8);
  const int boff1 = br * 64 + (((ac + 4) ^ (br & 7)) * 8);

  f32x4 acc[4][4] = {};

  STG(0, 0);
  STG(1, 1);

  for (int t = 0; t < NKT; ++t) {
    if (t == NKT - 1)
      asm volatile("s_waitcnt vmcnt(0)" ::: "memory");
    else
      asm volatile("s_waitcnt vmcnt(8)" ::: "memory");
    __builtin_amdgcn_s_barrier();
    __builtin_amdgcn_sched_barrier(0);
    const u16* la = &ls[t & 1][0][0];
    const u16* lb = &ls[t & 1][1][0];
    bf16x8 aF[2][4], bF[2][4];
#pragma unroll
    for (int f = 0; f < 4; ++f) {
      aF[0][f] = *(const bf16x8*)(la + aoff0 + f * 1024);
      aF[1][f] = *(const bf16x8*)(la + aoff1 + f * 1024);
      bF[0][f] = *(const bf16x8*)(lb + boff0 + f * 1024);
      bF[1][f] = *(const bf16x8*)(lb + boff1 + f * 1024);
    }
    asm volatile("s_waitcnt lgkmcnt(0)" ::: "memory");
    __builtin_amdgcn_sched_barrier(0);
    __builtin_amdgcn_s_barrier(); // all waves done reading buf[t&1]
    __builtin_amdgcn_sched_barrier(0);
    if (t + 2 < NKT) STG(t & 1, t + 2);
    __builtin_amdgcn_s_setprio(1);
#pragma unroll
    for (int ks = 0; ks < 2; ++ks)
#pragma unroll
      for (int fm = 0; fm < 4; ++fm)
#pragma unroll
        for (int fn = 0; fn < 4; ++fn)
          acc[fm][fn] = __builtin_amdgcn_mfma_f32_16x16x32_bf16(
              aF[ks][fm], bF[ks][fn], acc[fm][fn], 0, 0, 0);
    __builtin_amdgcn_s_setprio(0);
  }
#undef STG

  int r0 = tm * 128 + wm * 64 + (lane >> 4) * 4;
  int c0 = tn * 128 + wn * 64 + (lane & 15);

  if (MODE == 2) {
    u16* P = OB + (size_t)z * 4194304;
#pragma unroll
    for (int fm = 0; fm < 4; ++fm)
#pragma unroll
      for (int fn = 0; fn < 4; ++fn)
#pragma unroll
        for (int i = 0; i < 4; ++i)
          P[(size_t)(r0 + fm * 16 + i) * 2048 + (c0 + fn * 16)] =
              f2bf(acc[fm][fn][i]);
  } else {
    float* Ob = OF + (size_t)z * 2097152;
#pragma unroll
    for (int fm = 0; fm < 4; ++fm)
#pragma unroll
      for (int fn = 0; fn < 4; ++fn)
#pragma unroll
        for (int i = 0; i < 4; ++i)
          Ob[(size_t)(r0 + fm * 16 + i) * 1024 + (c0 + fn * 16)] = acc[fm][fn][i];
  }
}

// ---------------- causal row softmax over bf16 scores, in place ----------------
// Only processes the causal width ncol = ((q>>7)+1)*128; PV never reads beyond.
__global__ __launch_bounds__(256) void softmax_causal_kernel(u16* __restrict__ P) {
  int wid = threadIdx.x >> 6, lane = threadIdx.x & 63;
  int row = blockIdx.x * 4 + wid; // 0..8191
  int b = row >> 11, q = row & 2047;
  int nit = (q >> 7) + 1; // # of 128-col groups (warp-uniform)
  u16* rp = P + ((size_t)b * S_ + q) * S_;

  float vals[32];
  float m = -1e30f;
#pragma unroll
  for (int it = 0; it < 16; ++it)
    if (it < nit) {
      int s0 = it * 128 + lane * 2;
      u32 u = *(const u32*)(rp + s0);
      float v0 = bf2f((u16)u) * SCALE_;
      float v1 = bf2f((u16)(u >> 16)) * SCALE_;
      v0 = (s0 <= q) ? v0 : -1e30f;
      v1 = (s0 + 1 <= q) ? v1 : -1e30f;
      vals[2 * it] = v0;
      vals[2 * it + 1] = v1;
      m = fmaxf(m, fmaxf(v0, v1));
    }
#pragma unroll
  for (int off = 32; off; off >>= 1) m = fmaxf(m, __shfl_xor(m, off, 64));

  float l = 0.f;
#pragma unroll
  for (int it = 0; it < 16; ++it)
    if (it < nit) {
      vals[2 * it] = __expf(vals[2 * it] - m);
      vals[2 * it + 1] = __expf(vals[2 * it + 1] - m);
      l += vals[2 * it] + vals[2 * it + 1];
    }
#pragma unroll
  for (int off = 32; off; off >>= 1) l += __shfl_xor(l, off, 64);
  float inv = 1.0f / l;

#pragma unroll
  for (int it = 0; it < 16; ++it)
    if (it < nit) {
      int s0 = it * 128 + lane * 2;
      u32 o = (u32)f2bf(vals[2 * it] * inv) |
              ((u32)f2bf(vals[2 * it + 1] * inv) << 16);
      *(u32*)(rp + s0) = o;
    }
}

extern "C" void kernel_launch(void* const* d_in, const int* in_sizes, int n_in,
                              void* d_out, int out_size, void* d_ws, size_t ws_size,
                              hipStream_t stream) {
  const float* x = (const float*)d_in[0];
  const float* Wq = (const float*)d_in[1];
  const float* Wk = (const float*)d_in[2];
  const float* Wv = (const float*)d_in[3];
  float* out = (float*)d_out;

  u16* ws = (u16*)d_ws;
  u16* Xb = ws;              // [8192][1024]
  u16* Qb = ws + 8388608;    // [4][2048][1024]
  u16* Kb = ws + 16777216;   // [4][2048][1024]
  u16* Vt = ws + 25165824;   // [4][1024][2048] (e-major)
  u16* Pm = ws + 33554432;   // [4][2048][2048]
  u16* Wcat = ws + 50331648; // [3072][1024]: Wq^T | Wk^T | Wv^T

  cvt_x_kernel<<<8192, 256, 0, stream>>>(x, Xb);
  transpose_w_kernel<<<dim3(32, 32), dim3(32, 8), 0, stream>>>(Wq, Wcat);
  transpose_w_kernel<<<dim3(32, 32), dim3(32, 8), 0, stream>>>(Wk, Wcat + 1048576);
  transpose_w_kernel<<<dim3(32, 32), dim3(32, 8), 0, stream>>>(Wv, Wcat + 2097152);

  // fused QKV projection: M=8192, N=3072, K=1024
  gemm256<<<dim3(32, 12, 1), 512, 0, stream>>>(Xb, Wcat, Qb, Kb, Vt);

  // scores: per batch M=N=2048, K=1024, 128^2 tiles, causal tile skip
  gemm128<2><<<dim3(16, 16, 4), 256, 0, stream>>>(Qb, Kb, Pm, nullptr);

  softmax_causal_kernel<<<2048, 256, 0, stream>>>(Pm);

  // PV: per batch M=2048, N=1024, K=(tm+1)*128, 128^2 tiles, balanced pairing
  gemm128<3><<<dim3(16, 8, 4), 256, 0, stream>>>(Pm, Vt, nullptr, out);
}